// Round 1
// baseline (248.401 us; speedup 1.0000x reference)
//
#include <hip/hip_runtime.h>

#define NN 8192      // nodes
#define FI 512       // in features
#define FH 512       // hidden features

// ---------------- degree count ----------------
__global__ void k_deg(const int* __restrict__ dst, int E, int* __restrict__ deg) {
    int i = blockIdx.x * blockDim.x + threadIdx.x;
    if (i < E) atomicAdd(&deg[dst[i]], 1);
}

__global__ void k_dinv(const int* __restrict__ deg, float* __restrict__ dinv) {
    int v = blockIdx.x * blockDim.x + threadIdx.x;
    if (v < NN) dinv[v] = rsqrtf((float)(deg[v] + 1));   // +1 self loop
}

// ---------------- prefix scan over row lengths (deg+1) ----------------
__global__ __launch_bounds__(1024) void k_scan(const int* __restrict__ deg,
                                               int* __restrict__ row_ptr) {
    __shared__ int lds[1024];
    int tid = threadIdx.x;
    int base = tid * 8;
    int l[8]; int s = 0;
    #pragma unroll
    for (int u = 0; u < 8; ++u) { l[u] = deg[base + u] + 1; s += l[u]; }
    lds[tid] = s;
    __syncthreads();
    for (int off = 1; off < 1024; off <<= 1) {
        int add = (tid >= off) ? lds[tid - off] : 0;
        __syncthreads();
        lds[tid] += add;
        __syncthreads();
    }
    int run = lds[tid] - s;  // exclusive prefix
    #pragma unroll
    for (int u = 0; u < 8; ++u) { row_ptr[base + u] = run; run += l[u]; }
    if (tid == 1023) row_ptr[NN] = lds[1023];
}

// ---------------- CSR fill (edges + self loops) ----------------
__global__ void k_fill(const int* __restrict__ src, const int* __restrict__ dst, int E,
                       const float* __restrict__ dinv, const int* __restrict__ row_ptr,
                       int* __restrict__ cursor,
                       int* __restrict__ csr_src, float* __restrict__ csr_w) {
    int i = blockIdx.x * blockDim.x + threadIdx.x;
    if (i < E) {
        int s = src[i], d = dst[i];
        int p = row_ptr[d] + atomicAdd(&cursor[d], 1);
        csr_src[p] = s;
        csr_w[p]   = dinv[s] * dinv[d];
    } else if (i < E + NN) {
        int v = i - E;
        int p = row_ptr[v] + atomicAdd(&cursor[v], 1);
        csr_src[p] = v;
        csr_w[p]   = dinv[v] * dinv[v];
    }
}

// ---------------- fp32 tiled GEMM: C[8192,512] = A[8192,512] @ B[512,512] ----------------
__global__ __launch_bounds__(256) void k_gemm1(const float* __restrict__ A,
                                               const float* __restrict__ B,
                                               float* __restrict__ C) {
    __shared__ float As[16][64];
    __shared__ float Bs[16][64];
    int tid = threadIdx.x;
    int tx = tid & 15, ty = tid >> 4;
    int bm = blockIdx.y * 64;
    int bn = blockIdx.x * 64;
    float c[4][4] = {};
    int arow = tid >> 2;           // 0..63
    int acol = (tid & 3) * 4;      // 0,4,8,12
    int brow = tid >> 4;           // 0..15
    int bcol = (tid & 15) * 4;     // 0..60

    for (int kk = 0; kk < FI; kk += 16) {
        float4 av = *reinterpret_cast<const float4*>(&A[(size_t)(bm + arow) * FI + kk + acol]);
        float4 bv = *reinterpret_cast<const float4*>(&B[(size_t)(kk + brow) * FH + bn + bcol]);
        As[acol + 0][arow] = av.x;
        As[acol + 1][arow] = av.y;
        As[acol + 2][arow] = av.z;
        As[acol + 3][arow] = av.w;
        *reinterpret_cast<float4*>(&Bs[brow][bcol]) = bv;
        __syncthreads();
        #pragma unroll
        for (int k = 0; k < 16; ++k) {
            float4 a = *reinterpret_cast<const float4*>(&As[k][ty * 4]);
            float4 b = *reinterpret_cast<const float4*>(&Bs[k][tx * 4]);
            c[0][0] += a.x * b.x; c[0][1] += a.x * b.y; c[0][2] += a.x * b.z; c[0][3] += a.x * b.w;
            c[1][0] += a.y * b.x; c[1][1] += a.y * b.y; c[1][2] += a.y * b.z; c[1][3] += a.y * b.w;
            c[2][0] += a.z * b.x; c[2][1] += a.z * b.y; c[2][2] += a.z * b.z; c[2][3] += a.z * b.w;
            c[3][0] += a.w * b.x; c[3][1] += a.w * b.y; c[3][2] += a.w * b.z; c[3][3] += a.w * b.w;
        }
        __syncthreads();
    }
    #pragma unroll
    for (int r = 0; r < 4; ++r) {
        float4 v = make_float4(c[r][0], c[r][1], c[r][2], c[r][3]);
        *reinterpret_cast<float4*>(&C[(size_t)(bm + ty * 4 + r) * FH + bn + tx * 4]) = v;
    }
}

// ---------------- aggregation 1: agg1[v] = relu(sum_nbr w * h1[src] + b1) ----------------
__global__ __launch_bounds__(256) void k_agg1(const float* __restrict__ h1,
                                              const int* __restrict__ row_ptr,
                                              const int* __restrict__ csr_src,
                                              const float* __restrict__ csr_w,
                                              const float* __restrict__ b1,
                                              float* __restrict__ agg1) {
    int v = blockIdx.x;
    int t = threadIdx.x;
    float acc0 = 0.f, acc1 = 0.f;
    int p0 = row_ptr[v], p1 = row_ptr[v + 1];
    for (int p = p0; p < p1; ++p) {
        int s  = csr_src[p];
        float w = csr_w[p];
        acc0 += w * h1[(size_t)s * FH + t];
        acc1 += w * h1[(size_t)s * FH + t + 256];
    }
    agg1[(size_t)v * FH + t]       = fmaxf(acc0 + b1[t], 0.f);
    agg1[(size_t)v * FH + t + 256] = fmaxf(acc1 + b1[t + 256], 0.f);
}

// ---------------- z[v] = dot(agg1[v,:], W2[:,0]) ----------------
__global__ __launch_bounds__(256) void k_gemv(const float* __restrict__ agg1,
                                              const float* __restrict__ W2,
                                              float* __restrict__ z) {
    int wave = threadIdx.x >> 6;
    int lane = threadIdx.x & 63;
    int v = blockIdx.x * 4 + wave;
    float s = 0.f;
    #pragma unroll
    for (int u = 0; u < FH; u += 64)
        s += agg1[(size_t)v * FH + u + lane] * W2[u + lane];
    #pragma unroll
    for (int off = 32; off; off >>= 1) s += __shfl_down(s, off);
    if (lane == 0) z[v] = s;
}

// ---------------- aggregation 2 (scalar) + ohe ----------------
__global__ void k_node(const float* __restrict__ z,
                       const int* __restrict__ row_ptr,
                       const int* __restrict__ csr_src,
                       const float* __restrict__ csr_w,
                       const float* __restrict__ b2,
                       const float* __restrict__ o,
                       const float* __restrict__ Wl,
                       const float* __restrict__ bl,
                       float* __restrict__ h2, float* __restrict__ ohe) {
    int v = blockIdx.x * blockDim.x + threadIdx.x;
    if (v >= NN) return;
    float acc = 0.f;
    int p1 = row_ptr[v + 1];
    for (int p = row_ptr[v]; p < p1; ++p)
        acc += csr_w[p] * z[csr_src[p]];
    h2[v] = acc + b2[0];
    float4 ov = *reinterpret_cast<const float4*>(&o[(size_t)v * 4]);
    ohe[v] = ov.x * Wl[0] + ov.y * Wl[1] + ov.z * Wl[2] + ov.w * Wl[3] + bl[0];
}

// ---------------- out[i][j] = h2[j] + ohe[i], 268 MB write ----------------
__global__ __launch_bounds__(256) void k_out(const float* __restrict__ h2,
                                             const float* __restrict__ ohe,
                                             float4* __restrict__ out) {
    unsigned idx = blockIdx.x * blockDim.x + threadIdx.x;  // < N*N/4 = 16.7M
    int i  = idx >> 11;        // 2048 float4 per row
    int j4 = idx & 2047;
    float4 h = reinterpret_cast<const float4*>(h2)[j4];
    float oi = ohe[i];
    out[idx] = make_float4(h.x + oi, h.y + oi, h.z + oi, h.w + oi);
}

extern "C" void kernel_launch(void* const* d_in, const int* in_sizes, int n_in,
                              void* d_out, int out_size, void* d_ws, size_t ws_size,
                              hipStream_t stream) {
    const float* x  = (const float*)d_in[0];
    const float* o  = (const float*)d_in[1];
    const int*   ei = (const int*)d_in[2];
    const float* W1 = (const float*)d_in[3];
    const float* b1 = (const float*)d_in[4];
    const float* W2 = (const float*)d_in[5];
    const float* b2 = (const float*)d_in[6];
    const float* Wl = (const float*)d_in[7];
    const float* bl = (const float*)d_in[8];
    float* out = (float*)d_out;

    const int E = in_sizes[2] / 2;
    const int* src = ei;
    const int* dst = ei + E;

    // workspace carve-up (256B aligned)
    char* p = (char*)d_ws;
    auto alloc = [&](size_t bytes) {
        char* r = p;
        p += (bytes + 255) & ~(size_t)255;
        return r;
    };
    int*   deg     = (int*)  alloc(NN * 4);
    float* dinv    = (float*)alloc(NN * 4);
    int*   row_ptr = (int*)  alloc((NN + 1) * 4);
    int*   cursor  = (int*)  alloc(NN * 4);
    int*   csr_src = (int*)  alloc((size_t)(E + NN) * 4);
    float* csr_w   = (float*)alloc((size_t)(E + NN) * 4);
    float* h1      = (float*)alloc((size_t)NN * FH * 4);
    float* agg1    = (float*)alloc((size_t)NN * FH * 4);
    float* z       = (float*)alloc(NN * 4);
    float* h2      = (float*)alloc(NN * 4);
    float* ohe     = (float*)alloc(NN * 4);

    hipMemsetAsync(deg,    0, NN * 4, stream);
    hipMemsetAsync(cursor, 0, NN * 4, stream);

    k_deg <<<(E + 255) / 256, 256, 0, stream>>>(dst, E, deg);
    k_dinv<<<(NN + 255) / 256, 256, 0, stream>>>(deg, dinv);
    k_scan<<<1, 1024, 0, stream>>>(deg, row_ptr);
    k_fill<<<(E + NN + 255) / 256, 256, 0, stream>>>(src, dst, E, dinv, row_ptr, cursor,
                                                     csr_src, csr_w);
    k_gemm1<<<dim3(FH / 64, NN / 64), 256, 0, stream>>>(x, W1, h1);
    k_agg1<<<NN, 256, 0, stream>>>(h1, row_ptr, csr_src, csr_w, b1, agg1);
    k_gemv<<<NN / 4, 256, 0, stream>>>(agg1, W2, z);
    k_node<<<(NN + 255) / 256, 256, 0, stream>>>(z, row_ptr, csr_src, csr_w, b2,
                                                 o, Wl, bl, h2, ohe);
    k_out<<<(NN / 4) * (NN / 256), 256, 0, stream>>>(h2, ohe, (float4*)out);
}

// Round 2
// 218.468 us; speedup vs baseline: 1.1370x; 1.1370x over previous
//
#include <hip/hip_runtime.h>

#define NN 8192      // nodes
#define FI 512       // in features
#define FH 512       // hidden features
#define KSPLIT 1536  // 3 x 512 split-K for precision

typedef __attribute__((ext_vector_type(8))) short short8;
typedef __attribute__((ext_vector_type(4))) float f32x4;

__device__ __forceinline__ unsigned short f2bf(float f) {
    unsigned u = __float_as_uint(f);
    unsigned r = (u + 0x7fff + ((u >> 16) & 1)) >> 16;   // RNE
    return (unsigned short)r;
}
__device__ __forceinline__ float bf2f(unsigned short us) {
    return __uint_as_float((unsigned)us << 16);
}

#define GLOAD_LDS16(g, l)                                                        \
    __builtin_amdgcn_global_load_lds((__attribute__((address_space(1))) const void*)(g), \
                                     (__attribute__((address_space(3))) void*)(l), 16, 0, 0)

// ---------------- degree count ----------------
__global__ void k_deg(const int* __restrict__ dst, int E, int* __restrict__ deg) {
    int i = blockIdx.x * blockDim.x + threadIdx.x;
    if (i < E) atomicAdd(&deg[dst[i]], 1);
}

__global__ void k_dinv(const int* __restrict__ deg, float* __restrict__ dinv) {
    int v = blockIdx.x * blockDim.x + threadIdx.x;
    if (v < NN) dinv[v] = rsqrtf((float)(deg[v] + 1));   // +1 self loop
}

// ---------------- prefix scan over row lengths (deg+1) ----------------
__global__ __launch_bounds__(1024) void k_scan(const int* __restrict__ deg,
                                               int* __restrict__ row_ptr) {
    __shared__ int lds[1024];
    int tid = threadIdx.x;
    int base = tid * 8;
    int l[8]; int s = 0;
    #pragma unroll
    for (int u = 0; u < 8; ++u) { l[u] = deg[base + u] + 1; s += l[u]; }
    lds[tid] = s;
    __syncthreads();
    for (int off = 1; off < 1024; off <<= 1) {
        int add = (tid >= off) ? lds[tid - off] : 0;
        __syncthreads();
        lds[tid] += add;
        __syncthreads();
    }
    int run = lds[tid] - s;  // exclusive prefix
    #pragma unroll
    for (int u = 0; u < 8; ++u) { row_ptr[base + u] = run; run += l[u]; }
    if (tid == 1023) row_ptr[NN] = lds[1023];
}

// ---------------- CSR fill (edges + self loops) ----------------
__global__ void k_fill(const int* __restrict__ src, const int* __restrict__ dst, int E,
                       const float* __restrict__ dinv, const int* __restrict__ row_ptr,
                       int* __restrict__ cursor,
                       int* __restrict__ csr_src, float* __restrict__ csr_w) {
    int i = blockIdx.x * blockDim.x + threadIdx.x;
    if (i < E) {
        int s = src[i], d = dst[i];
        int p = row_ptr[d] + atomicAdd(&cursor[d], 1);
        csr_src[p] = s;
        csr_w[p]   = dinv[s] * dinv[d];
    } else if (i < E + NN) {
        int v = i - E;
        int p = row_ptr[v] + atomicAdd(&cursor[v], 1);
        csr_src[p] = v;
        csr_w[p]   = dinv[v] * dinv[v];
    }
}

// ---------------- split x into bf16 hi + lo residual ----------------
__global__ __launch_bounds__(256) void k_split_x(const float* __restrict__ x,
                                                 unsigned short* __restrict__ xh,
                                                 unsigned short* __restrict__ xl) {
    int i = blockIdx.x * blockDim.x + threadIdx.x;   // handles 4 floats
    float4 v = reinterpret_cast<const float4*>(x)[i];
    ushort4 h, l;
    h.x = f2bf(v.x); l.x = f2bf(v.x - bf2f(h.x));
    h.y = f2bf(v.y); l.y = f2bf(v.y - bf2f(h.y));
    h.z = f2bf(v.z); l.z = f2bf(v.z - bf2f(h.z));
    h.w = f2bf(v.w); l.w = f2bf(v.w - bf2f(h.w));
    reinterpret_cast<ushort4*>(xh)[i] = h;
    reinterpret_cast<ushort4*>(xl)[i] = l;
}

// ---------------- build W1t [n][KSPLIT] = [Wh ; Wh ; Wl] (k-contiguous per n) -------
__global__ __launch_bounds__(256) void k_wprep(const float* __restrict__ W1,
                                               unsigned short* __restrict__ W1t) {
    int idx = blockIdx.x * blockDim.x + threadIdx.x;  // 512*512
    int n = idx & 511, k = idx >> 9;
    float w = W1[(size_t)k * FH + n];                 // coalesced over n
    unsigned short wh = f2bf(w);
    unsigned short wl = f2bf(w - bf2f(wh));
    W1t[(size_t)n * KSPLIT + k]        = wh;
    W1t[(size_t)n * KSPLIT + 512 + k]  = wh;
    W1t[(size_t)n * KSPLIT + 1024 + k] = wl;
}

// ---------------- bf16 MFMA GEMM: h1[8192,512] = A'[8192,1536] @ B'[1536,512] -------
// A' segments: [xh | xl | xh]; B' = W1t rows (k-contiguous). Output bf16.
__global__ __launch_bounds__(256) void k_gemm(const unsigned short* __restrict__ xh,
                                              const unsigned short* __restrict__ xl,
                                              const unsigned short* __restrict__ W1t,
                                              unsigned short* __restrict__ h1) {
    __shared__ __align__(16) unsigned short As[128 * 32];
    __shared__ __align__(16) unsigned short Bs[128 * 32];
    int tid  = threadIdx.x;
    int lane = tid & 63;
    int wave = tid >> 6;
    int wm = wave >> 1, wn = wave & 1;           // 2x2 wave grid, 64x64 per wave
    int bm = blockIdx.y * 128, bn = blockIdx.x * 128;

    f32x4 acc[4][4] = {};

    int r  = lane & 15;       // fragment row/col within 16
    int s0 = lane >> 4;       // 16B k-slot 0..3

    for (int kt = 0; kt < KSPLIT / 32; ++kt) {
        int seg = kt >> 4;                        // 0,1,2
        const unsigned short* Abase = (seg == 1) ? xl : xh;
        int acol = (kt & 15) * 32;                // k offset within 512-wide segment
        int bcol = kt * 32;                       // k offset within 1536-wide W1t row

        #pragma unroll
        for (int t = 0; t < 2; ++t) {
            int q   = t * 256 + tid;              // 16B unit index, 0..511
            int row = q >> 2;
            int sl  = q & 3;
            int slg = sl ^ (row & 3);             // pre-swizzled source slot
            GLOAD_LDS16(Abase + (size_t)(bm + row) * FI + acol + slg * 8,
                        As + q * 8);
            GLOAD_LDS16(W1t + (size_t)(bn + row) * KSPLIT + bcol + slg * 8,
                        Bs + q * 8);
        }
        __syncthreads();

        short8 a[4], b[4];
        #pragma unroll
        for (int m = 0; m < 4; ++m) {
            int row = wm * 64 + m * 16 + r;
            int sl  = s0 ^ (row & 3);
            a[m] = *reinterpret_cast<const short8*>(As + row * 32 + sl * 8);
        }
        #pragma unroll
        for (int n = 0; n < 4; ++n) {
            int row = wn * 64 + n * 16 + r;
            int sl  = s0 ^ (row & 3);
            b[n] = *reinterpret_cast<const short8*>(Bs + row * 32 + sl * 8);
        }
        #pragma unroll
        for (int m = 0; m < 4; ++m)
            #pragma unroll
            for (int n = 0; n < 4; ++n)
                acc[m][n] = __builtin_amdgcn_mfma_f32_16x16x32_bf16(a[m], b[n], acc[m][n], 0, 0, 0);
        __syncthreads();
    }

    // C/D layout: col = lane&15, row = (lane>>4)*4 + reg  [m89-verified]
    #pragma unroll
    for (int m = 0; m < 4; ++m) {
        #pragma unroll
        for (int n = 0; n < 4; ++n) {
            int col = bn + wn * 64 + n * 16 + (lane & 15);
            int rw0 = bm + wm * 64 + m * 16 + (lane >> 4) * 4;
            #pragma unroll
            for (int reg = 0; reg < 4; ++reg)
                h1[(size_t)(rw0 + reg) * FH + col] = f2bf(acc[m][n][reg]);
        }
    }
}

// ------- fused: agg1[v] = relu(sum w*h1[src] + b1); z[v] = dot(agg1[v], W2) -------
__global__ __launch_bounds__(256) void k_agg(const unsigned short* __restrict__ h1,
                                             const int* __restrict__ row_ptr,
                                             const int* __restrict__ csr_src,
                                             const float* __restrict__ csr_w,
                                             const float* __restrict__ b1,
                                             const float* __restrict__ W2,
                                             float* __restrict__ z) {
    int v = blockIdx.x;
    int t = threadIdx.x;           // owns feats 2t, 2t+1
    float a0 = 0.f, a1 = 0.f;
    int p0 = row_ptr[v], p1 = row_ptr[v + 1];
    for (int p = p0; p < p1; ++p) {
        int s   = csr_src[p];
        float w = csr_w[p];
        unsigned pair = *reinterpret_cast<const unsigned*>(h1 + (size_t)s * FH + 2 * t);
        a0 += w * bf2f((unsigned short)(pair & 0xffff));
        a1 += w * bf2f((unsigned short)(pair >> 16));
    }
    float2 bb = reinterpret_cast<const float2*>(b1)[t];
    float2 ww = reinterpret_cast<const float2*>(W2)[t];
    float val = fmaxf(a0 + bb.x, 0.f) * ww.x + fmaxf(a1 + bb.y, 0.f) * ww.y;
    #pragma unroll
    for (int off = 32; off; off >>= 1) val += __shfl_down(val, off);
    __shared__ float red[4];
    int lane = t & 63, wave = t >> 6;
    if (lane == 0) red[wave] = val;
    __syncthreads();
    if (t == 0) z[v] = red[0] + red[1] + red[2] + red[3];
}

// ---------------- aggregation 2 (scalar) + ohe ----------------
__global__ void k_node(const float* __restrict__ z,
                       const int* __restrict__ row_ptr,
                       const int* __restrict__ csr_src,
                       const float* __restrict__ csr_w,
                       const float* __restrict__ b2,
                       const float* __restrict__ o,
                       const float* __restrict__ Wl,
                       const float* __restrict__ bl,
                       float* __restrict__ h2, float* __restrict__ ohe) {
    int v = blockIdx.x * blockDim.x + threadIdx.x;
    if (v >= NN) return;
    float acc = 0.f;
    int p1 = row_ptr[v + 1];
    for (int p = row_ptr[v]; p < p1; ++p)
        acc += csr_w[p] * z[csr_src[p]];
    h2[v] = acc + b2[0];
    float4 ov = *reinterpret_cast<const float4*>(&o[(size_t)v * 4]);
    ohe[v] = ov.x * Wl[0] + ov.y * Wl[1] + ov.z * Wl[2] + ov.w * Wl[3] + bl[0];
}

// ---------------- out[i][j] = h2[j] + ohe[i], 268 MB write ----------------
__global__ __launch_bounds__(256) void k_out(const float* __restrict__ h2,
                                             const float* __restrict__ ohe,
                                             float4* __restrict__ out) {
    unsigned idx = blockIdx.x * blockDim.x + threadIdx.x;  // < N*N/4 = 16.7M
    int i  = idx >> 11;        // 2048 float4 per row
    int j4 = idx & 2047;
    float4 h = reinterpret_cast<const float4*>(h2)[j4];
    float oi = ohe[i];
    out[idx] = make_float4(h.x + oi, h.y + oi, h.z + oi, h.w + oi);
}

extern "C" void kernel_launch(void* const* d_in, const int* in_sizes, int n_in,
                              void* d_out, int out_size, void* d_ws, size_t ws_size,
                              hipStream_t stream) {
    const float* x  = (const float*)d_in[0];
    const float* o  = (const float*)d_in[1];
    const int*   ei = (const int*)d_in[2];
    const float* W1 = (const float*)d_in[3];
    const float* b1 = (const float*)d_in[4];
    const float* W2 = (const float*)d_in[5];
    const float* b2 = (const float*)d_in[6];
    const float* Wl = (const float*)d_in[7];
    const float* bl = (const float*)d_in[8];
    float* out = (float*)d_out;

    const int E = in_sizes[2] / 2;
    const int* src = ei;
    const int* dst = ei + E;

    // workspace carve-up (256B aligned)
    char* p = (char*)d_ws;
    auto alloc = [&](size_t bytes) {
        char* r = p;
        p += (bytes + 255) & ~(size_t)255;
        return r;
    };
    int*   deg     = (int*)  alloc(NN * 4);
    float* dinv    = (float*)alloc(NN * 4);
    int*   row_ptr = (int*)  alloc((NN + 1) * 4);
    int*   cursor  = (int*)  alloc(NN * 4);
    int*   csr_src = (int*)  alloc((size_t)(E + NN) * 4);
    float* csr_w   = (float*)alloc((size_t)(E + NN) * 4);
    unsigned short* xh  = (unsigned short*)alloc((size_t)NN * FI * 2);
    unsigned short* xl  = (unsigned short*)alloc((size_t)NN * FI * 2);
    unsigned short* W1t = (unsigned short*)alloc((size_t)FH * KSPLIT * 2);
    unsigned short* h1  = (unsigned short*)alloc((size_t)NN * FH * 2);
    float* z       = (float*)alloc(NN * 4);
    float* h2      = (float*)alloc(NN * 4);
    float* ohe     = (float*)alloc(NN * 4);

    hipMemsetAsync(deg,    0, NN * 4, stream);
    hipMemsetAsync(cursor, 0, NN * 4, stream);

    k_deg  <<<(E + 255) / 256, 256, 0, stream>>>(dst, E, deg);
    k_dinv <<<(NN + 255) / 256, 256, 0, stream>>>(deg, dinv);
    k_scan <<<1, 1024, 0, stream>>>(deg, row_ptr);
    k_fill <<<(E + NN + 255) / 256, 256, 0, stream>>>(src, dst, E, dinv, row_ptr, cursor,
                                                      csr_src, csr_w);
    k_split_x<<<(NN * FI / 4) / 256, 256, 0, stream>>>(x, xh, xl);
    k_wprep  <<<(FI * FH) / 256, 256, 0, stream>>>(W1, W1t);
    k_gemm   <<<dim3(FH / 128, NN / 128), 256, 0, stream>>>(xh, xl, W1t, h1);
    k_agg    <<<NN, 256, 0, stream>>>(h1, row_ptr, csr_src, csr_w, b1, W2, z);
    k_node   <<<(NN + 255) / 256, 256, 0, stream>>>(z, row_ptr, csr_src, csr_w, b2,
                                                    o, Wl, bl, h2, ohe);
    k_out    <<<(NN / 4) * (NN / 256), 256, 0, stream>>>(h2, ohe, (float4*)out);
}

// Round 3
// 168.712 us; speedup vs baseline: 1.4723x; 1.2949x over previous
//
#include <hip/hip_runtime.h>

#define NN 8192      // nodes
#define FI 512       // in features
#define FH 512       // hidden features

typedef __attribute__((ext_vector_type(8))) short short8;
typedef __attribute__((ext_vector_type(4))) float f32x4;

__device__ __forceinline__ unsigned short f2bf(float f) {
    unsigned u = __float_as_uint(f);
    unsigned r = (u + 0x7fff + ((u >> 16) & 1)) >> 16;   // RNE
    return (unsigned short)r;
}
__device__ __forceinline__ float bf2f(unsigned short us) {
    return __uint_as_float((unsigned)us << 16);
}

#define GLOAD_LDS16(g, l)                                                        \
    __builtin_amdgcn_global_load_lds((__attribute__((address_space(1))) const void*)(g), \
                                     (__attribute__((address_space(3))) void*)(l), 16, 0, 0)

// ---------------- zero deg/cursor (replaces hipMemsetAsync) ----------------
__global__ void k_zero(int* __restrict__ deg, int* __restrict__ cursor) {
    int i = blockIdx.x * blockDim.x + threadIdx.x;
    if (i < NN) { deg[i] = 0; cursor[i] = 0; }
}

// ---------------- degree count ----------------
__global__ void k_deg(const int* __restrict__ dst, int E, int* __restrict__ deg) {
    int i = blockIdx.x * blockDim.x + threadIdx.x;
    if (i < E) atomicAdd(&deg[dst[i]], 1);
}

// ---------------- prefix scan over row lengths (deg+1) + dinv ----------------
__global__ __launch_bounds__(1024) void k_scan(const int* __restrict__ deg,
                                               int* __restrict__ row_ptr,
                                               float* __restrict__ dinv) {
    __shared__ int lds[1024];
    int tid = threadIdx.x;
    int base = tid * 8;
    int l[8]; int s = 0;
    #pragma unroll
    for (int u = 0; u < 8; ++u) {
        l[u] = deg[base + u] + 1;                       // +1 self loop
        dinv[base + u] = rsqrtf((float)l[u]);
        s += l[u];
    }
    lds[tid] = s;
    __syncthreads();
    for (int off = 1; off < 1024; off <<= 1) {
        int add = (tid >= off) ? lds[tid - off] : 0;
        __syncthreads();
        lds[tid] += add;
        __syncthreads();
    }
    int run = lds[tid] - s;  // exclusive prefix
    #pragma unroll
    for (int u = 0; u < 8; ++u) { row_ptr[base + u] = run; run += l[u]; }
    if (tid == 1023) row_ptr[NN] = lds[1023];
}

// ---------------- CSR fill (edges + self loops) ----------------
__global__ void k_fill(const int* __restrict__ src, const int* __restrict__ dst, int E,
                       const float* __restrict__ dinv, const int* __restrict__ row_ptr,
                       int* __restrict__ cursor,
                       int* __restrict__ csr_src, float* __restrict__ csr_w) {
    int i = blockIdx.x * blockDim.x + threadIdx.x;
    if (i < E) {
        int s = src[i], d = dst[i];
        int p = row_ptr[d] + atomicAdd(&cursor[d], 1);
        csr_src[p] = s;
        csr_w[p]   = dinv[s] * dinv[d];
    } else if (i < E + NN) {
        int v = i - E;
        int p = row_ptr[v] + atomicAdd(&cursor[v], 1);
        csr_src[p] = v;
        csr_w[p]   = dinv[v] * dinv[v];
    }
}

// ---------------- convert x to bf16 ----------------
__global__ __launch_bounds__(256) void k_cvt_x(const float* __restrict__ x,
                                               unsigned short* __restrict__ xb) {
    int i = blockIdx.x * blockDim.x + threadIdx.x;   // handles 4 floats
    float4 v = reinterpret_cast<const float4*>(x)[i];
    ushort4 h;
    h.x = f2bf(v.x); h.y = f2bf(v.y); h.z = f2bf(v.z); h.w = f2bf(v.w);
    reinterpret_cast<ushort4*>(xb)[i] = h;
}

// ---------------- build W1t [n][k] bf16 (k-contiguous per n) ----------------
__global__ __launch_bounds__(256) void k_wprep(const float* __restrict__ W1,
                                               unsigned short* __restrict__ W1t) {
    int idx = blockIdx.x * blockDim.x + threadIdx.x;  // 512*512
    int k = idx & 511, n = idx >> 9;
    float w = W1[(size_t)k * FH + n];
    W1t[(size_t)n * FI + k] = f2bf(w);                // coalesced write
}

// ---------------- bf16 MFMA GEMM: h1[8192,512] = xb[8192,512] @ W1t^T -------
__global__ __launch_bounds__(256) void k_gemm(const unsigned short* __restrict__ xb,
                                              const unsigned short* __restrict__ W1t,
                                              unsigned short* __restrict__ h1) {
    __shared__ __align__(16) unsigned short As[128 * 32];
    __shared__ __align__(16) unsigned short Bs[128 * 32];
    int tid  = threadIdx.x;
    int lane = tid & 63;
    int wave = tid >> 6;
    int wm = wave >> 1, wn = wave & 1;           // 2x2 wave grid, 64x64 per wave
    int bm = blockIdx.y * 128, bn = blockIdx.x * 128;

    f32x4 acc[4][4] = {};

    int r  = lane & 15;       // fragment row/col within 16
    int s0 = lane >> 4;       // 16B k-slot 0..3

    for (int kt = 0; kt < FI / 32; ++kt) {
        int col = kt * 32;

        #pragma unroll
        for (int t = 0; t < 2; ++t) {
            int q   = t * 256 + tid;              // 16B unit index, 0..511
            int row = q >> 2;
            int sl  = q & 3;
            int slg = sl ^ (row & 3);             // pre-swizzled source slot
            GLOAD_LDS16(xb  + (size_t)(bm + row) * FI + col + slg * 8, As + q * 8);
            GLOAD_LDS16(W1t + (size_t)(bn + row) * FI + col + slg * 8, Bs + q * 8);
        }
        __syncthreads();

        short8 a[4], b[4];
        #pragma unroll
        for (int m = 0; m < 4; ++m) {
            int row = wm * 64 + m * 16 + r;
            int sl  = s0 ^ (row & 3);
            a[m] = *reinterpret_cast<const short8*>(As + row * 32 + sl * 8);
        }
        #pragma unroll
        for (int n = 0; n < 4; ++n) {
            int row = wn * 64 + n * 16 + r;
            int sl  = s0 ^ (row & 3);
            b[n] = *reinterpret_cast<const short8*>(Bs + row * 32 + sl * 8);
        }
        #pragma unroll
        for (int m = 0; m < 4; ++m)
            #pragma unroll
            for (int n = 0; n < 4; ++n)
                acc[m][n] = __builtin_amdgcn_mfma_f32_16x16x32_bf16(a[m], b[n], acc[m][n], 0, 0, 0);
        __syncthreads();
    }

    // C/D layout: col = lane&15, row = (lane>>4)*4 + reg  [m89-verified]
    #pragma unroll
    for (int m = 0; m < 4; ++m) {
        #pragma unroll
        for (int n = 0; n < 4; ++n) {
            int col = bn + wn * 64 + n * 16 + (lane & 15);
            int rw0 = bm + wm * 64 + m * 16 + (lane >> 4) * 4;
            #pragma unroll
            for (int reg = 0; reg < 4; ++reg)
                h1[(size_t)(rw0 + reg) * FH + col] = f2bf(acc[m][n][reg]);
        }
    }
}

// ------- fused: agg1[v] = relu(sum w*h1[src] + b1); z[v] = dot(agg1[v], W2) -------
// one wave per node; lane owns feats [lane*8, lane*8+8)
__global__ __launch_bounds__(256) void k_agg(const unsigned short* __restrict__ h1,
                                             const int* __restrict__ row_ptr,
                                             const int* __restrict__ csr_src,
                                             const float* __restrict__ csr_w,
                                             const float* __restrict__ b1,
                                             const float* __restrict__ W2,
                                             float* __restrict__ z) {
    int lane = threadIdx.x & 63;
    int v = blockIdx.x * 4 + (threadIdx.x >> 6);
    float acc[8] = {};
    int p0 = row_ptr[v], p1 = row_ptr[v + 1];
    for (int p = p0; p < p1; ++p) {
        int s   = csr_src[p];
        float w = csr_w[p];
        short8 hv = *reinterpret_cast<const short8*>(h1 + (size_t)s * FH + lane * 8);
        #pragma unroll
        for (int j = 0; j < 8; ++j) acc[j] += w * bf2f((unsigned short)hv[j]);
    }
    const float4* b4 = reinterpret_cast<const float4*>(b1 + lane * 8);
    const float4* w4 = reinterpret_cast<const float4*>(W2 + lane * 8);
    float4 b0 = b4[0], bs1 = b4[1];
    float4 w0 = w4[0], ws1 = w4[1];
    float val = fmaxf(acc[0] + b0.x, 0.f) * w0.x + fmaxf(acc[1] + b0.y, 0.f) * w0.y
              + fmaxf(acc[2] + b0.z, 0.f) * w0.z + fmaxf(acc[3] + b0.w, 0.f) * w0.w
              + fmaxf(acc[4] + bs1.x, 0.f) * ws1.x + fmaxf(acc[5] + bs1.y, 0.f) * ws1.y
              + fmaxf(acc[6] + bs1.z, 0.f) * ws1.z + fmaxf(acc[7] + bs1.w, 0.f) * ws1.w;
    #pragma unroll
    for (int off = 32; off; off >>= 1) val += __shfl_down(val, off);
    if (lane == 0) z[v] = val;
}

// ---------------- aggregation 2 (scalar) + ohe ----------------
__global__ void k_node(const float* __restrict__ z,
                       const int* __restrict__ row_ptr,
                       const int* __restrict__ csr_src,
                       const float* __restrict__ csr_w,
                       const float* __restrict__ b2,
                       const float* __restrict__ o,
                       const float* __restrict__ Wl,
                       const float* __restrict__ bl,
                       float* __restrict__ h2, float* __restrict__ ohe) {
    int v = blockIdx.x * blockDim.x + threadIdx.x;
    if (v >= NN) return;
    float acc = 0.f;
    int p1 = row_ptr[v + 1];
    for (int p = row_ptr[v]; p < p1; ++p)
        acc += csr_w[p] * z[csr_src[p]];
    h2[v] = acc + b2[0];
    float4 ov = *reinterpret_cast<const float4*>(&o[(size_t)v * 4]);
    ohe[v] = ov.x * Wl[0] + ov.y * Wl[1] + ov.z * Wl[2] + ov.w * Wl[3] + bl[0];
}

// ---------------- out[i][j] = h2[j] + ohe[i], 268 MB write ----------------
__global__ __launch_bounds__(256) void k_out(const float* __restrict__ h2,
                                             const float* __restrict__ ohe,
                                             float4* __restrict__ out) {
    unsigned idx = blockIdx.x * blockDim.x + threadIdx.x;  // < N*N/4 = 16.7M
    int i  = idx >> 11;        // 2048 float4 per row
    int j4 = idx & 2047;
    float4 h = reinterpret_cast<const float4*>(h2)[j4];
    float oi = ohe[i];
    out[idx] = make_float4(h.x + oi, h.y + oi, h.z + oi, h.w + oi);
}

extern "C" void kernel_launch(void* const* d_in, const int* in_sizes, int n_in,
                              void* d_out, int out_size, void* d_ws, size_t ws_size,
                              hipStream_t stream) {
    const float* x  = (const float*)d_in[0];
    const float* o  = (const float*)d_in[1];
    const int*   ei = (const int*)d_in[2];
    const float* W1 = (const float*)d_in[3];
    const float* b1 = (const float*)d_in[4];
    const float* W2 = (const float*)d_in[5];
    const float* b2 = (const float*)d_in[6];
    const float* Wl = (const float*)d_in[7];
    const float* bl = (const float*)d_in[8];
    float* out = (float*)d_out;

    const int E = in_sizes[2] / 2;
    const int* src = ei;
    const int* dst = ei + E;

    // workspace carve-up (256B aligned)
    char* p = (char*)d_ws;
    auto alloc = [&](size_t bytes) {
        char* r = p;
        p += (bytes + 255) & ~(size_t)255;
        return r;
    };
    int*   deg     = (int*)  alloc(NN * 4);
    float* dinv    = (float*)alloc(NN * 4);
    int*   row_ptr = (int*)  alloc((NN + 1) * 4);
    int*   cursor  = (int*)  alloc(NN * 4);
    int*   csr_src = (int*)  alloc((size_t)(E + NN) * 4);
    float* csr_w   = (float*)alloc((size_t)(E + NN) * 4);
    unsigned short* xb  = (unsigned short*)alloc((size_t)NN * FI * 2);
    unsigned short* W1t = (unsigned short*)alloc((size_t)FH * FI * 2);
    unsigned short* h1  = (unsigned short*)alloc((size_t)NN * FH * 2);
    float* z       = (float*)alloc(NN * 4);
    float* h2      = (float*)alloc(NN * 4);
    float* ohe     = (float*)alloc(NN * 4);

    k_zero <<<NN / 256, 256, 0, stream>>>(deg, cursor);
    k_deg  <<<(E + 255) / 256, 256, 0, stream>>>(dst, E, deg);
    k_scan <<<1, 1024, 0, stream>>>(deg, row_ptr, dinv);
    k_fill <<<(E + NN + 255) / 256, 256, 0, stream>>>(src, dst, E, dinv, row_ptr, cursor,
                                                      csr_src, csr_w);
    k_cvt_x<<<(NN * FI / 4) / 256, 256, 0, stream>>>(x, xb);
    k_wprep<<<(FI * FH) / 256, 256, 0, stream>>>(W1, W1t);
    k_gemm <<<dim3(FH / 128, NN / 128), 256, 0, stream>>>(xb, W1t, h1);
    k_agg  <<<NN / 4, 256, 0, stream>>>(h1, row_ptr, csr_src, csr_w, b1, W2, z);
    k_node <<<(NN + 255) / 256, 256, 0, stream>>>(z, row_ptr, csr_src, csr_w, b2,
                                                  o, Wl, bl, h2, ohe);
    k_out  <<<(NN / 4) * (NN / 256), 256, 0, stream>>>(h2, ohe, (float4*)out);
}

// Round 4
// 152.649 us; speedup vs baseline: 1.6273x; 1.1052x over previous
//
#include <hip/hip_runtime.h>

#define NN 8192      // nodes
#define FI 512       // in features
#define FH 512       // hidden features

typedef __attribute__((ext_vector_type(8))) short short8;
typedef __attribute__((ext_vector_type(4))) float f32x4;

__device__ __forceinline__ unsigned short f2bf(float f) {
    unsigned u = __float_as_uint(f);
    unsigned r = (u + 0x7fff + ((u >> 16) & 1)) >> 16;   // RNE
    return (unsigned short)r;
}
__device__ __forceinline__ float bf2f(unsigned short us) {
    return __uint_as_float((unsigned)us << 16);
}

#define GLOAD_LDS16(g, l)                                                        \
    __builtin_amdgcn_global_load_lds((__attribute__((address_space(1))) const void*)(g), \
                                     (__attribute__((address_space(3))) void*)(l), 16, 0, 0)

// ------- fused prep: cvt x->bf16 (blocks 0..4095), W1 transpose->bf16 (4096..5119),
//         zero deg/cursor (5120..5151) -------
__global__ __launch_bounds__(256) void k_prep(const float* __restrict__ x,
                                              const float* __restrict__ W1,
                                              unsigned short* __restrict__ xb,
                                              unsigned short* __restrict__ W1t,
                                              int* __restrict__ deg,
                                              int* __restrict__ cursor) {
    int b = blockIdx.x, t = threadIdx.x;
    if (b < 4096) {
        int i = b * 256 + t;
        float4 v = reinterpret_cast<const float4*>(x)[i];
        ushort4 h;
        h.x = f2bf(v.x); h.y = f2bf(v.y); h.z = f2bf(v.z); h.w = f2bf(v.w);
        reinterpret_cast<ushort4*>(xb)[i] = h;
    } else if (b < 5120) {
        int idx = (b - 4096) * 256 + t;
        int k = idx & 511, n = idx >> 9;
        W1t[(size_t)n * FI + k] = f2bf(W1[(size_t)k * FH + n]);
    } else {
        int i = (b - 5120) * 256 + t;
        deg[i] = 0; cursor[i] = 0;
    }
}

// ---------------- degree count ----------------
__global__ void k_deg(const int* __restrict__ dst, int E, int* __restrict__ deg) {
    int i = blockIdx.x * blockDim.x + threadIdx.x;
    if (i < E) atomicAdd(&deg[dst[i]], 1);
}

// ---------------- prefix scan over row lengths (deg+1) + dinv ----------------
__global__ __launch_bounds__(1024) void k_scan(const int* __restrict__ deg,
                                               int* __restrict__ row_ptr,
                                               float* __restrict__ dinv) {
    __shared__ int lds[1024];
    int tid = threadIdx.x;
    int base = tid * 8;
    int l[8]; int s = 0;
    #pragma unroll
    for (int u = 0; u < 8; ++u) {
        l[u] = deg[base + u] + 1;                       // +1 self loop
        dinv[base + u] = rsqrtf((float)l[u]);
        s += l[u];
    }
    lds[tid] = s;
    __syncthreads();
    for (int off = 1; off < 1024; off <<= 1) {
        int add = (tid >= off) ? lds[tid - off] : 0;
        __syncthreads();
        lds[tid] += add;
        __syncthreads();
    }
    int run = lds[tid] - s;  // exclusive prefix
    #pragma unroll
    for (int u = 0; u < 8; ++u) { row_ptr[base + u] = run; run += l[u]; }
    if (tid == 1023) row_ptr[NN] = lds[1023];
}

// ---------------- CSR fill: packed (src, weight-bits) pairs ----------------
__global__ void k_fill(const int* __restrict__ src, const int* __restrict__ dst, int E,
                       const float* __restrict__ dinv, const int* __restrict__ row_ptr,
                       int* __restrict__ cursor, int2* __restrict__ csr) {
    int i = blockIdx.x * blockDim.x + threadIdx.x;
    if (i < E) {
        int s = src[i], d = dst[i];
        int p = row_ptr[d] + atomicAdd(&cursor[d], 1);
        csr[p] = make_int2(s, __float_as_int(dinv[s] * dinv[d]));
    } else if (i < E + NN) {
        int v = i - E;
        int p = row_ptr[v] + atomicAdd(&cursor[v], 1);
        csr[p] = make_int2(v, __float_as_int(dinv[v] * dinv[v]));
    }
}

// ---------------- bf16 MFMA GEMM: h1[8192,512] = xb[8192,512] @ W1t^T -------
__global__ __launch_bounds__(256) void k_gemm(const unsigned short* __restrict__ xb,
                                              const unsigned short* __restrict__ W1t,
                                              unsigned short* __restrict__ h1) {
    __shared__ __align__(16) unsigned short As[128 * 32];
    __shared__ __align__(16) unsigned short Bs[128 * 32];
    int tid  = threadIdx.x;
    int lane = tid & 63;
    int wave = tid >> 6;
    int wm = wave >> 1, wn = wave & 1;           // 2x2 wave grid, 64x64 per wave
    int bm = blockIdx.y * 128, bn = blockIdx.x * 128;

    f32x4 acc[4][4] = {};

    int r  = lane & 15;       // fragment row/col within 16
    int s0 = lane >> 4;       // 16B k-slot 0..3

    for (int kt = 0; kt < FI / 32; ++kt) {
        int col = kt * 32;

        #pragma unroll
        for (int t = 0; t < 2; ++t) {
            int q   = t * 256 + tid;              // 16B unit index, 0..511
            int row = q >> 2;
            int sl  = q & 3;
            int slg = sl ^ (row & 3);             // pre-swizzled source slot
            GLOAD_LDS16(xb  + (size_t)(bm + row) * FI + col + slg * 8, As + q * 8);
            GLOAD_LDS16(W1t + (size_t)(bn + row) * FI + col + slg * 8, Bs + q * 8);
        }
        __syncthreads();

        short8 a[4], b[4];
        #pragma unroll
        for (int m = 0; m < 4; ++m) {
            int row = wm * 64 + m * 16 + r;
            int sl  = s0 ^ (row & 3);
            a[m] = *reinterpret_cast<const short8*>(As + row * 32 + sl * 8);
        }
        #pragma unroll
        for (int n = 0; n < 4; ++n) {
            int row = wn * 64 + n * 16 + r;
            int sl  = s0 ^ (row & 3);
            b[n] = *reinterpret_cast<const short8*>(Bs + row * 32 + sl * 8);
        }
        #pragma unroll
        for (int m = 0; m < 4; ++m)
            #pragma unroll
            for (int n = 0; n < 4; ++n)
                acc[m][n] = __builtin_amdgcn_mfma_f32_16x16x32_bf16(a[m], b[n], acc[m][n], 0, 0, 0);
        __syncthreads();
    }

    // C/D layout: col = lane&15, row = (lane>>4)*4 + reg  [m89-verified]
    #pragma unroll
    for (int m = 0; m < 4; ++m) {
        #pragma unroll
        for (int n = 0; n < 4; ++n) {
            int col = bn + wn * 64 + n * 16 + (lane & 15);
            int rw0 = bm + wm * 64 + m * 16 + (lane >> 4) * 4;
            #pragma unroll
            for (int reg = 0; reg < 4; ++reg)
                h1[(size_t)(rw0 + reg) * FH + col] = f2bf(acc[m][n][reg]);
        }
    }
}

// ------- fused: agg1[v] = relu(sum w*h1[src] + b1); z[v] = dot(agg1[v], W2) -------
// one wave per node; lane owns feats [lane*8, lane*8+8)
// chunked-broadcast: wave loads 64 (src,w) pairs coalesced, shfl-broadcasts them
__global__ __launch_bounds__(256) void k_agg(const unsigned short* __restrict__ h1,
                                             const int* __restrict__ row_ptr,
                                             const int2* __restrict__ csr,
                                             const float* __restrict__ b1,
                                             const float* __restrict__ W2,
                                             float* __restrict__ z) {
    int lane = threadIdx.x & 63;
    int v = blockIdx.x * 4 + (threadIdx.x >> 6);
    float acc[8] = {};
    int p0 = row_ptr[v], p1 = row_ptr[v + 1];
    for (int base = p0; base < p1; base += 64) {
        int cnt = p1 - base; if (cnt > 64) cnt = 64;
        int2 sw = (lane < cnt) ? csr[base + lane] : make_int2(0, 0);
        int j = 0;
        for (; j + 4 <= cnt; j += 4) {
            int   s0 = __shfl(sw.x, j),     s1 = __shfl(sw.x, j + 1);
            int   s2 = __shfl(sw.x, j + 2), s3 = __shfl(sw.x, j + 3);
            float w0 = __int_as_float(__shfl(sw.y, j));
            float w1 = __int_as_float(__shfl(sw.y, j + 1));
            float w2 = __int_as_float(__shfl(sw.y, j + 2));
            float w3 = __int_as_float(__shfl(sw.y, j + 3));
            short8 hv0 = *reinterpret_cast<const short8*>(h1 + (size_t)s0 * FH + lane * 8);
            short8 hv1 = *reinterpret_cast<const short8*>(h1 + (size_t)s1 * FH + lane * 8);
            short8 hv2 = *reinterpret_cast<const short8*>(h1 + (size_t)s2 * FH + lane * 8);
            short8 hv3 = *reinterpret_cast<const short8*>(h1 + (size_t)s3 * FH + lane * 8);
            #pragma unroll
            for (int q = 0; q < 8; ++q) acc[q] += w0 * bf2f((unsigned short)hv0[q]);
            #pragma unroll
            for (int q = 0; q < 8; ++q) acc[q] += w1 * bf2f((unsigned short)hv1[q]);
            #pragma unroll
            for (int q = 0; q < 8; ++q) acc[q] += w2 * bf2f((unsigned short)hv2[q]);
            #pragma unroll
            for (int q = 0; q < 8; ++q) acc[q] += w3 * bf2f((unsigned short)hv3[q]);
        }
        for (; j < cnt; ++j) {
            int   sj = __shfl(sw.x, j);
            float wj = __int_as_float(__shfl(sw.y, j));
            short8 hv = *reinterpret_cast<const short8*>(h1 + (size_t)sj * FH + lane * 8);
            #pragma unroll
            for (int q = 0; q < 8; ++q) acc[q] += wj * bf2f((unsigned short)hv[q]);
        }
    }
    const float4* b4 = reinterpret_cast<const float4*>(b1 + lane * 8);
    const float4* w4 = reinterpret_cast<const float4*>(W2 + lane * 8);
    float4 b0 = b4[0], bs1 = b4[1];
    float4 w0 = w4[0], ws1 = w4[1];
    float val = fmaxf(acc[0] + b0.x, 0.f) * w0.x + fmaxf(acc[1] + b0.y, 0.f) * w0.y
              + fmaxf(acc[2] + b0.z, 0.f) * w0.z + fmaxf(acc[3] + b0.w, 0.f) * w0.w
              + fmaxf(acc[4] + bs1.x, 0.f) * ws1.x + fmaxf(acc[5] + bs1.y, 0.f) * ws1.y
              + fmaxf(acc[6] + bs1.z, 0.f) * ws1.z + fmaxf(acc[7] + bs1.w, 0.f) * ws1.w;
    #pragma unroll
    for (int off = 32; off; off >>= 1) val += __shfl_down(val, off);
    if (lane == 0) z[v] = val;
}

// ---------------- aggregation 2 (scalar) + ohe ----------------
__global__ void k_node(const float* __restrict__ z,
                       const int* __restrict__ row_ptr,
                       const int2* __restrict__ csr,
                       const float* __restrict__ b2,
                       const float* __restrict__ o,
                       const float* __restrict__ Wl,
                       const float* __restrict__ bl,
                       float* __restrict__ h2, float* __restrict__ ohe) {
    int v = blockIdx.x * blockDim.x + threadIdx.x;
    if (v >= NN) return;
    float acc = 0.f;
    int p1 = row_ptr[v + 1];
    for (int p = row_ptr[v]; p < p1; ++p) {
        int2 sw = csr[p];
        acc += __int_as_float(sw.y) * z[sw.x];
    }
    h2[v] = acc + b2[0];
    float4 ov = *reinterpret_cast<const float4*>(&o[(size_t)v * 4]);
    ohe[v] = ov.x * Wl[0] + ov.y * Wl[1] + ov.z * Wl[2] + ov.w * Wl[3] + bl[0];
}

// ---------------- out[i][j] = h2[j] + ohe[i], 268 MB write ----------------
__global__ __launch_bounds__(256) void k_out(const float* __restrict__ h2,
                                             const float* __restrict__ ohe,
                                             float4* __restrict__ out) {
    unsigned idx = blockIdx.x * blockDim.x + threadIdx.x;  // < N*N/4 = 16.7M
    int i  = idx >> 11;        // 2048 float4 per row
    int j4 = idx & 2047;
    float4 h = reinterpret_cast<const float4*>(h2)[j4];
    float oi = ohe[i];
    out[idx] = make_float4(h.x + oi, h.y + oi, h.z + oi, h.w + oi);
}

extern "C" void kernel_launch(void* const* d_in, const int* in_sizes, int n_in,
                              void* d_out, int out_size, void* d_ws, size_t ws_size,
                              hipStream_t stream) {
    const float* x  = (const float*)d_in[0];
    const float* o  = (const float*)d_in[1];
    const int*   ei = (const int*)d_in[2];
    const float* W1 = (const float*)d_in[3];
    const float* b1 = (const float*)d_in[4];
    const float* W2 = (const float*)d_in[5];
    const float* b2 = (const float*)d_in[6];
    const float* Wl = (const float*)d_in[7];
    const float* bl = (const float*)d_in[8];
    float* out = (float*)d_out;

    const int E = in_sizes[2] / 2;
    const int* src = ei;
    const int* dst = ei + E;

    // workspace carve-up (256B aligned)
    char* p = (char*)d_ws;
    auto alloc = [&](size_t bytes) {
        char* r = p;
        p += (bytes + 255) & ~(size_t)255;
        return r;
    };
    int*   deg     = (int*)  alloc(NN * 4);
    float* dinv    = (float*)alloc(NN * 4);
    int*   row_ptr = (int*)  alloc((NN + 1) * 4);
    int*   cursor  = (int*)  alloc(NN * 4);
    int2*  csr     = (int2*) alloc((size_t)(E + NN) * 8);
    unsigned short* xb  = (unsigned short*)alloc((size_t)NN * FI * 2);
    unsigned short* W1t = (unsigned short*)alloc((size_t)FH * FI * 2);
    unsigned short* h1  = (unsigned short*)alloc((size_t)NN * FH * 2);
    float* z       = (float*)alloc(NN * 4);
    float* h2      = (float*)alloc(NN * 4);
    float* ohe     = (float*)alloc(NN * 4);

    k_prep <<<5152, 256, 0, stream>>>(x, W1, xb, W1t, deg, cursor);
    k_deg  <<<(E + 255) / 256, 256, 0, stream>>>(dst, E, deg);
    k_scan <<<1, 1024, 0, stream>>>(deg, row_ptr, dinv);
    k_fill <<<(E + NN + 255) / 256, 256, 0, stream>>>(src, dst, E, dinv, row_ptr, cursor, csr);
    k_gemm <<<dim3(FH / 128, NN / 128), 256, 0, stream>>>(xb, W1t, h1);
    k_agg  <<<NN / 4, 256, 0, stream>>>(h1, row_ptr, csr, b1, W2, z);
    k_node <<<(NN + 255) / 256, 256, 0, stream>>>(z, row_ptr, csr, b2, o, Wl, bl, h2, ohe);
    k_out  <<<(NN / 4) * (NN / 256), 256, 0, stream>>>(h2, ohe, (float4*)out);
}